// Round 3
// baseline (607.805 us; speedup 1.0000x reference)
//
#include <hip/hip_runtime.h>

#define NB     16
#define NPTS   32768
#define NC     64
#define RES    32
#define R3     32768
#define EPSV   1e-6f
#define SLICES 8
#define NPT    (NB * NPTS)   // 524288 points
#define NBKT   (NB * 512)    // 8192 buckets of 64 voxels each

// ---------------------------------------------------------------------------
// Stats pass A: per-(batch,slice) partial coordinate sums (double accum).
// ---------------------------------------------------------------------------
__global__ __launch_bounds__(256) void stats_partial_kernel(const float* __restrict__ coords,
                                                            double* __restrict__ psum) {
    const int blk = blockIdx.x;
    const int b = blk >> 3, s = blk & (SLICES - 1);
    const int cnt = NPTS / SLICES;                       // 4096
    const float* cb = coords + ((size_t)b * NPTS + (size_t)s * cnt) * 3;

    double sx = 0.0, sy = 0.0, sz = 0.0;
    for (int n = threadIdx.x; n < cnt; n += 256) {
        sx += (double)cb[n * 3 + 0];
        sy += (double)cb[n * 3 + 1];
        sz += (double)cb[n * 3 + 2];
    }
    __shared__ double sd[256];
    const int t = threadIdx.x;
    sd[t] = sx; __syncthreads();
    for (int o = 128; o > 0; o >>= 1) { if (t < o) sd[t] += sd[t + o]; __syncthreads(); }
    if (t == 0) psum[blk * 3 + 0] = sd[0];
    __syncthreads();
    sd[t] = sy; __syncthreads();
    for (int o = 128; o > 0; o >>= 1) { if (t < o) sd[t] += sd[t + o]; __syncthreads(); }
    if (t == 0) psum[blk * 3 + 1] = sd[0];
    __syncthreads();
    sd[t] = sz; __syncthreads();
    for (int o = 128; o > 0; o >>= 1) { if (t < o) sd[t] += sd[t + o]; __syncthreads(); }
    if (t == 0) psum[blk * 3 + 2] = sd[0];
}

// ---------------------------------------------------------------------------
// Stats pass B: per-(batch,slice) partial max ||c - mean||.
// ---------------------------------------------------------------------------
__global__ __launch_bounds__(256) void maxnorm_partial_kernel(const float* __restrict__ coords,
                                                              const double* __restrict__ psum,
                                                              float* __restrict__ pmax,
                                                              float* __restrict__ stats) {
    const int blk = blockIdx.x;
    const int b = blk >> 3, s = blk & (SLICES - 1);
    const int cnt = NPTS / SLICES;

    double dx = 0.0, dy = 0.0, dz = 0.0;
    for (int i = 0; i < SLICES; i++) {
        dx += psum[(b * SLICES + i) * 3 + 0];
        dy += psum[(b * SLICES + i) * 3 + 1];
        dz += psum[(b * SLICES + i) * 3 + 2];
    }
    const float mx = (float)(dx / (double)NPTS);
    const float my = (float)(dy / (double)NPTS);
    const float mz = (float)(dz / (double)NPTS);

    if (s == 0 && threadIdx.x == 0) {
        stats[b * 4 + 0] = mx;
        stats[b * 4 + 1] = my;
        stats[b * 4 + 2] = mz;
    }

    const float* cb = coords + ((size_t)b * NPTS + (size_t)s * cnt) * 3;
    float mn = 0.0f;
    for (int n = threadIdx.x; n < cnt; n += 256) {
        float ax = cb[n * 3 + 0] - mx;
        float ay = cb[n * 3 + 1] - my;
        float az = cb[n * 3 + 2] - mz;
        mn = fmaxf(mn, sqrtf(ax * ax + ay * ay + az * az));
    }
    __shared__ float sf[256];
    const int t = threadIdx.x;
    sf[t] = mn; __syncthreads();
    for (int o = 128; o > 0; o >>= 1) { if (t < o) sf[t] = fmaxf(sf[t], sf[t + o]); __syncthreads(); }
    if (t == 0) pmax[blk] = sf[0];
}

// Stats pass C: final per-batch max -> divisor.
__global__ __launch_bounds__(64) void stats_final_kernel(const float* __restrict__ pmax,
                                                         float* __restrict__ stats) {
    const int b = threadIdx.x;
    if (b < NB) {
        float m = 0.0f;
        for (int i = 0; i < SLICES; i++) m = fmaxf(m, pmax[b * SLICES + i]);
        stats[b * 4 + 3] = m * 2.0f + EPSV;
    }
}

// ---------------------------------------------------------------------------
// Pass 1: per point -> normalized coords out, voxel id to pvox, bucket histogram.
// One thread per point.
// ---------------------------------------------------------------------------
__global__ __launch_bounds__(256) void hist_kernel(const float* __restrict__ coords,
                                                   const float* __restrict__ stats,
                                                   float* __restrict__ nc_out,
                                                   unsigned* __restrict__ pvox,
                                                   unsigned* __restrict__ hist) {
    const int p = blockIdx.x * 256 + threadIdx.x;
    const int b = p >> 15;

    const float mx = stats[b * 4 + 0];
    const float my = stats[b * 4 + 1];
    const float mz = stats[b * 4 + 2];
    const float s  = stats[b * 4 + 3];

    const float nx = (coords[(size_t)p * 3 + 0] - mx) / s + 0.5f;
    const float ny = (coords[(size_t)p * 3 + 1] - my) / s + 0.5f;
    const float nz = (coords[(size_t)p * 3 + 2] - mz) / s + 0.5f;

    nc_out[(size_t)p * 3 + 0] = nx;
    nc_out[(size_t)p * 3 + 1] = ny;
    nc_out[(size_t)p * 3 + 2] = nz;

    int vx = (int)rintf(nx * (float)(RES - 1));
    int vy = (int)rintf(ny * (float)(RES - 1));
    int vz = (int)rintf(nz * (float)(RES - 1));
    vx = min(max(vx, 0), RES - 1);
    vy = min(max(vy, 0), RES - 1);
    vz = min(max(vz, 0), RES - 1);
    const unsigned vox = (unsigned)(vx * (RES * RES) + vy * RES + vz);

    pvox[p] = vox;
    atomicAdd(&hist[((unsigned)b << 9) | (vox >> 6)], 1u);
}

// ---------------------------------------------------------------------------
// Pass 2: exclusive scan of the 8192 bucket counts -> cursor (= start offsets).
// Single block of 1024 threads, 8 entries per thread.
// ---------------------------------------------------------------------------
__global__ __launch_bounds__(1024) void scan_kernel(const unsigned* __restrict__ hist,
                                                    unsigned* __restrict__ cursor) {
    __shared__ unsigned s[1024];
    const int t = threadIdx.x;
    unsigned loc[8], sum = 0;
#pragma unroll
    for (int i = 0; i < 8; i++) { loc[i] = hist[t * 8 + i]; sum += loc[i]; }
    s[t] = sum; __syncthreads();
    for (int off = 1; off < 1024; off <<= 1) {
        unsigned v = (t >= off) ? s[t - off] : 0u;
        __syncthreads();
        s[t] += v;
        __syncthreads();
    }
    unsigned run = s[t] - sum;          // exclusive base for this thread's 8 entries
#pragma unroll
    for (int i = 0; i < 8; i++) { cursor[t * 8 + i] = run; run += loc[i]; }
}

// ---------------------------------------------------------------------------
// Pass 3: scatter point records into bucket-sorted order.
// rec = (local_voxel[6b] << 19) | point_id[19b].  After this pass,
// cursor[bkt] == end offset of bucket (start = end - hist[bkt]).
// ---------------------------------------------------------------------------
__global__ __launch_bounds__(256) void sort_kernel(const unsigned* __restrict__ pvox,
                                                   unsigned* __restrict__ cursor,
                                                   unsigned* __restrict__ recs) {
    const int p = blockIdx.x * 256 + threadIdx.x;
    const unsigned vox = pvox[p];
    const unsigned b = (unsigned)(p >> 15);
    const unsigned bkt = (b << 9) | (vox >> 6);
    const unsigned slot = atomicAdd(&cursor[bkt], 1u);
    recs[slot] = ((vox & 63u) << 19) | (unsigned)p;
}

// ---------------------------------------------------------------------------
// Pass 4: one block per bucket (64-voxel output tile).  Waves walk the
// bucket's points: coalesced 256B feature load, LDS-atomic accumulate into
// acc[64 vox][64 ch] (+1 pad col for conflict-free transposed read).  Then
// write the finished tile: out0[b][c][v0+vl] = acc[vl][c]/max(cnt,1).
// Empty buckets emit a zero tile -> no output memset needed anywhere.
// ---------------------------------------------------------------------------
__global__ __launch_bounds__(256) void gather_kernel(const float* __restrict__ features,
                                                     const unsigned* __restrict__ recs,
                                                     const unsigned* __restrict__ cursor,
                                                     const unsigned* __restrict__ hist,
                                                     float* __restrict__ out0) {
    const int bkt  = blockIdx.x;
    const int b    = bkt >> 9;
    const int v0   = (bkt & 511) << 6;
    const int tid  = threadIdx.x;
    const int lane = tid & 63;
    const int w    = tid >> 6;

    __shared__ float acc[64][65];
    __shared__ float cnt[64];

    for (int i = tid; i < 64 * 65; i += 256) ((float*)acc)[i] = 0.0f;
    if (tid < 64) cnt[tid] = 0.0f;
    __syncthreads();

    const unsigned end = cursor[bkt];
    const unsigned n   = hist[bkt];
    unsigned i = end - n + (unsigned)w;

    // 2-way unrolled: expose two independent feature loads per iteration
    for (; i + 4 < end; i += 8) {
        const unsigned r0 = recs[i];
        const unsigned r1 = recs[i + 4];
        const float f0 = features[((size_t)(r0 & 0x7FFFFu) << 6) + lane];
        const float f1 = features[((size_t)(r1 & 0x7FFFFu) << 6) + lane];
        atomicAdd(&acc[r0 >> 19][lane], f0);
        atomicAdd(&acc[r1 >> 19][lane], f1);
        if (lane == 0) {
            atomicAdd(&cnt[r0 >> 19], 1.0f);
            atomicAdd(&cnt[r1 >> 19], 1.0f);
        }
    }
    if (i < end) {
        const unsigned r0 = recs[i];
        const float f0 = features[((size_t)(r0 & 0x7FFFFu) << 6) + lane];
        atomicAdd(&acc[r0 >> 19][lane], f0);
        if (lane == 0) atomicAdd(&cnt[r0 >> 19], 1.0f);
    }
    __syncthreads();

    float* o = out0 + ((size_t)b << 21) + v0;
#pragma unroll
    for (int k = 0; k < 16; k++) {
        const int f  = k * 256 + tid;
        const int c  = f >> 6;
        const int vl = f & 63;
        o[((size_t)c << 15) + vl] = acc[vl][c] / fmaxf(cnt[vl], 1.0f);
    }
}

extern "C" void kernel_launch(void* const* d_in, const int* in_sizes, int n_in,
                              void* d_out, int out_size, void* d_ws, size_t ws_size,
                              hipStream_t stream) {
    const float* features = (const float*)d_in[0];   // [16,32768,64] f32
    const float* coords   = (const float*)d_in[1];   // [16,32768,3]  f32

    float* out0   = (float*)d_out;                               // [16,64,32,32,32]
    float* nc_out = (float*)d_out + (size_t)NB * NC * R3;        // [16,32768,3]

    // ws layout (~4.3 MB total)
    char* ws = (char*)d_ws;
    float*    stats  = (float*)ws;                       // 256 B
    double*   psum   = (double*)(ws + 256);              // 3 KB
    float*    pmax   = (float*)(ws + 3584);              // 512 B
    unsigned* hist   = (unsigned*)(ws + 4096);           // 32 KB
    unsigned* cursor = (unsigned*)(ws + 4096 + 32768);   // 32 KB
    unsigned* pvox   = (unsigned*)(ws + 4096 + 65536);   // 2 MB
    unsigned* recs   = (unsigned*)(ws + 4096 + 65536 + (size_t)NPT * 4);  // 2 MB

    hipMemsetAsync(hist, 0, NBKT * sizeof(unsigned), stream);

    stats_partial_kernel<<<NB * SLICES, 256, 0, stream>>>(coords, psum);
    maxnorm_partial_kernel<<<NB * SLICES, 256, 0, stream>>>(coords, psum, pmax, stats);
    stats_final_kernel<<<1, 64, 0, stream>>>(pmax, stats);

    hist_kernel<<<NPT / 256, 256, 0, stream>>>(coords, stats, nc_out, pvox, hist);
    scan_kernel<<<1, 1024, 0, stream>>>(hist, cursor);
    sort_kernel<<<NPT / 256, 256, 0, stream>>>(pvox, cursor, recs);
    gather_kernel<<<NBKT, 256, 0, stream>>>(features, recs, cursor, hist, out0);
}